// Round 11
// baseline (173.645 us; speedup 1.0000x reference)
//
#include <hip/hip_runtime.h>
#include <cstddef>

#define NB   32
#define CTXD 1024
#define FFD  8192
#define HD   256
#define WD   256
#define NPIX 65536
#define EPSF 1e-12f

typedef __attribute__((ext_vector_type(8))) short bf16x8;
typedef __attribute__((ext_vector_type(4))) float f32x4;

// ---------- helpers ----------

__device__ __forceinline__ float ftanh(float x){
  float ax = fabsf(x);
  float e  = __expf(2.0f*ax);
  float r  = 1.0f - 2.0f*__builtin_amdgcn_rcpf(e + 1.0f);
  return copysignf(r, x);
}

__device__ __forceinline__ unsigned short f2bf(float f){
  unsigned u = __float_as_uint(f);
  unsigned r = (u + 0x7FFFu + ((u >> 16) & 1u)) >> 16;   // RTNE
  return (unsigned short)r;
}
__device__ __forceinline__ float bf2f(unsigned short s){
  return __uint_as_float((unsigned)s << 16);
}

// split f32 -> 3 bf16 terms (residual ~2^-27 relative)
__device__ __forceinline__ void split3(float f, unsigned short& s0,
                                       unsigned short& s1, unsigned short& s2){
  s0 = f2bf(f);
  float r1 = f - bf2f(s0);
  s1 = f2bf(r1);
  float r2 = r1 - bf2f(s1);
  s2 = f2bf(r2);
}

// async global->LDS, 16B per lane; dst wave-uniform base + lane*16
__device__ __forceinline__ void gload_lds16(const float* g, float* l){
  __builtin_amdgcn_global_load_lds(
      (__attribute__((address_space(1))) void*)const_cast<float*>(g),
      (__attribute__((address_space(3))) void*)l, 16, 0, 0);
}

__device__ __forceinline__ void block_reduce4(float& a, float& b, float& c, float& d){
  for (int off = 32; off > 0; off >>= 1){
    a += __shfl_down(a, off); b += __shfl_down(b, off);
    c += __shfl_down(c, off); d += __shfl_down(d, off);
  }
  __shared__ float lds[16];
  int wid = threadIdx.x >> 6, lane = threadIdx.x & 63;
  if (lane == 0){ lds[wid*4+0]=a; lds[wid*4+1]=b; lds[wid*4+2]=c; lds[wid*4+3]=d; }
  __syncthreads();
  a = (lds[0]+lds[4])+(lds[8]+lds[12]);
  b = (lds[1]+lds[5])+(lds[9]+lds[13]);
  c = (lds[2]+lds[6])+(lds[10]+lds[14]);
  d = (lds[3]+lds[7])+(lds[11]+lds[15]);
}

// per-pixel recompute core shared by k_scan / k_final (must stay identical)
__device__ __forceinline__ void pixel_core(
    const float* __restrict__ lds, int h, int w, int pix,
    float cw0, float cw1, float cw2, float cw3, float cb,
    const float* __restrict__ wmod, const float* __restrict__ wstat,
    float& r_, float& i_, float& p_, float& q_){
  float sk[4];
  #pragma unroll
  for (int k = 0; k < 4; ++k){
    float acc = 0.f;
    #pragma unroll
    for (int r = 0; r < 4; ++r){
      int kr = k*4 + r;
      float u  = lds[kr*512 + h];
      float vv = lds[kr*512 + 256 + w];
      float tt = ftanh(u*vv);
      float cwr = (r==0)?cw0:(r==1)?cw1:(r==2)?cw2:cw3;
      acc += (k==0) ? cwr*tt : tt;
    }
    sk[k] = acc;
  }
  sk[0] += cb;
  float m0 = sk[0]*wmod[0*NPIX+pix];
  float m1 = sk[1]*wmod[1*NPIX+pix];
  float m2 = sk[2]*wmod[2*NPIX+pix];
  float m3 = sk[3]*wmod[3*NPIX+pix];
  float2 A1 = *(const float2*)(wstat + (size_t)(NPIX + pix)*2);
  r_ = A1.x*m0 - A1.y*m1;
  i_ = A1.x*m1 - A1.y*m0;
  p_ = m2; q_ = m3;
}

// ---------- kernels ----------

// split x [32][1024] f32 -> packed B-fragment layout, zero red[]
__global__ __launch_bounds__(256) void k_prep(
    const float* __restrict__ x, unsigned short* __restrict__ P,
    float* __restrict__ red){
  int g = blockIdx.x*256 + threadIdx.x;      // 4096 = 32 rows x 128 groups
  if (g < 64) red[g] = 0.0f;
  int b = g >> 7, grp = g & 127;
  int koff = grp*8;
  int c = grp >> 2, kg = grp & 3;
  const float* src = x + (size_t)b*CTXD + koff;
  float4 v0 = *(const float4*)(src), v1 = *(const float4*)(src+4);
  float vv[8] = {v0.x,v0.y,v0.z,v0.w,v1.x,v1.y,v1.z,v1.w};
  bf16x8 a0, a1, a2;
  #pragma unroll
  for (int e = 0; e < 8; ++e){
    unsigned short s0,s1,s2; split3(vv[e],s0,s1,s2);
    a0[e]=(short)s0; a1[e]=(short)s1; a2[e]=(short)s2;
  }
  size_t base = (size_t)c*3072 + (b>>4)*512 + kg*128 + (b&15)*8;
  *(bf16x8*)(P + base)        = a0;
  *(bf16x8*)(P + base + 1024) = a1;
  *(bf16x8*)(P + base + 2048) = a2;
}

// 1KB-burst streaming split-bf16 MFMA GEMM.
// Block = 2 waves x 16 features, k-slice of 256. Each wave stages its 16 rows
// as 16 async 1KB page-aligned bursts (global_load_lds, XOR-swizzled source),
// one vmcnt(0), then computes 8 K=32 chunks self-contained. No barriers.
// Cp[z*4+kc (G1) | kc (G2)][f][b] partials; k_reduce* sums.
__global__ __launch_bounds__(128) void k_gemm_stream(
    const float* __restrict__ W0, const float* __restrict__ W1,
    const unsigned short* __restrict__ BP,
    float* __restrict__ Cp, int K, size_t zstride){
  __shared__ float tile[8192];              // 2 waves x 16 rows x 256 floats
  const int t    = threadIdx.x;
  const int wv   = t >> 6, lane = t & 63;
  const int row  = lane & 15, kg = lane >> 4;
  const int f0   = blockIdx.x*32 + wv*16;
  const int kc   = blockIdx.y;
  const float* __restrict__ W = blockIdx.z ? W1 : W0;
  const int kb   = kc*256;                  // k float-offset of this slice

  // stage: row r -> LDS pieces 0..63 (linear); lane L fetches global piece
  // L^(r&7) so that reads can use the same XOR (bank-conflict-free).
  float* ldst = tile + wv*4096;
  const float* wbase = W + (size_t)f0*K + kb;
  #pragma unroll
  for (int r = 0; r < 16; ++r){
    const float* src = wbase + (size_t)r*K + ((lane ^ (r & 7)) << 2);
    gload_lds16(src, ldst + r*256);
  }
  // B chunk 0 (L2-hot pack)
  const unsigned short* pb = BP + (size_t)(kc*8)*3072 + kg*128 + row*8;
  bf16x8 b0 = *(const bf16x8*)(pb);
  bf16x8 b1 = *(const bf16x8*)(pb +  512);
  bf16x8 b2 = *(const bf16x8*)(pb + 1024);
  bf16x8 b3 = *(const bf16x8*)(pb + 1536);
  bf16x8 b4 = *(const bf16x8*)(pb + 2048);
  bf16x8 b5 = *(const bf16x8*)(pb + 2560);
  asm volatile("s_waitcnt vmcnt(0)" ::: "memory");
  __builtin_amdgcn_sched_barrier(0);

  f32x4 acc0 = {0.f,0.f,0.f,0.f}, acc1 = {0.f,0.f,0.f,0.f};
  const float* lrow = tile + wv*4096 + row*256;
  const int sw = row & 7;
  #pragma unroll
  for (int c = 0; c < 8; ++c){
    bf16x8 cb0=b0, cb1=b1, cb2=b2, cb3=b3, cb4=b4, cb5=b5;
    if (c < 7){                              // prefetch next chunk's B
      const unsigned short* pn = pb + (size_t)(c+1)*3072;
      b0 = *(const bf16x8*)(pn);
      b1 = *(const bf16x8*)(pn +  512);
      b2 = *(const bf16x8*)(pn + 1024);
      b3 = *(const bf16x8*)(pn + 1536);
      b4 = *(const bf16x8*)(pn + 2048);
      b5 = *(const bf16x8*)(pn + 2560);
    }
    // A fragment: global pieces q,q+1 of this row live at LDS pieces ^sw
    int q = c*8 + kg*2;
    float4 lo = *(const float4*)(lrow + ((q      ^ sw) << 2));
    float4 hi = *(const float4*)(lrow + (((q+1) ^ sw) << 2));
    bf16x8 a0, a1, a2;
    float wv8[8] = {lo.x,lo.y,lo.z,lo.w,hi.x,hi.y,hi.z,hi.w};
    #pragma unroll
    for (int e = 0; e < 8; ++e){
      unsigned short s0,s1,s2; split3(wv8[e],s0,s1,s2);
      a0[e]=(short)s0; a1[e]=(short)s1; a2[e]=(short)s2;
    }
    acc0 = __builtin_amdgcn_mfma_f32_16x16x32_bf16(a0, cb0, acc0, 0,0,0);
    acc1 = __builtin_amdgcn_mfma_f32_16x16x32_bf16(a0, cb1, acc1, 0,0,0);
    acc0 = __builtin_amdgcn_mfma_f32_16x16x32_bf16(a0, cb2, acc0, 0,0,0);
    acc1 = __builtin_amdgcn_mfma_f32_16x16x32_bf16(a0, cb3, acc1, 0,0,0);
    acc0 = __builtin_amdgcn_mfma_f32_16x16x32_bf16(a1, cb0, acc0, 0,0,0);
    acc1 = __builtin_amdgcn_mfma_f32_16x16x32_bf16(a1, cb1, acc1, 0,0,0);
    acc0 = __builtin_amdgcn_mfma_f32_16x16x32_bf16(a0, cb4, acc0, 0,0,0);
    acc1 = __builtin_amdgcn_mfma_f32_16x16x32_bf16(a0, cb5, acc1, 0,0,0);
    acc0 = __builtin_amdgcn_mfma_f32_16x16x32_bf16(a1, cb2, acc0, 0,0,0);
    acc1 = __builtin_amdgcn_mfma_f32_16x16x32_bf16(a1, cb3, acc1, 0,0,0);
    acc0 = __builtin_amdgcn_mfma_f32_16x16x32_bf16(a2, cb0, acc0, 0,0,0);
    acc1 = __builtin_amdgcn_mfma_f32_16x16x32_bf16(a2, cb1, acc1, 0,0,0);
  }

  float* __restrict__ C = Cp + (size_t)blockIdx.z*zstride + (size_t)kc*(FFD*32);
  #pragma unroll
  for (int r = 0; r < 4; ++r){              // C/D: col=lane&15, row=kg*4+r
    int f = f0 + kg*4 + r;
    C[(size_t)f*32 + row]      = acc0[r];
    C[(size_t)f*32 + 16 + row] = acc1[r];
  }
}

// reduce for GEMM1 (both matrices), S=4
__global__ __launch_bounds__(256) void k_reduce1(
    const float* __restrict__ Cp, const float* __restrict__ bin,
    const float* __restrict__ bg, float* __restrict__ xtT,
    float* __restrict__ xgT){
  int g = blockIdx.x*256 + threadIdx.x;          // 524288
  int m = g >> 18, idx = g & 262143;
  int f = idx >> 5;
  const float* __restrict__ cp = Cp + (size_t)m*(4ull*FFD*32);
  float s = (m ? bg : bin)[f];
  #pragma unroll
  for (int sI = 0; sI < 4; ++sI) s += cp[(size_t)sI*(FFD*32) + idx];
  (m ? xgT : xtT)[idx] = s;
}

// reduce for GEMM2, S=32
__global__ __launch_bounds__(256) void k_reduce2(
    const float* __restrict__ Cp, const float* __restrict__ bias,
    float* __restrict__ outT){
  int g = blockIdx.x*256 + threadIdx.x;          // 262144
  int f = g >> 5;
  float s = bias[f];
  #pragma unroll
  for (int sI = 0; sI < 32; ++sI) s += Cp[(size_t)sI*(FFD*32) + g];
  outT[g] = s;
}

// norm over 2048-groups (ddof=1); ctx = nt*tanh(ng) -> packed B-fragment layout
__global__ __launch_bounds__(256) void k_normgate(
    const float* __restrict__ xtT, const float* __restrict__ xgT,
    unsigned short* __restrict__ P){
  int b = blockIdx.x >> 2, g4 = blockIdx.x & 3;
  int t = threadIdx.x;
  int f8 = g4*2048 + t*8;
  float vt[8], vg[8];
  float st=0.f, sst=0.f, sg=0.f, ssg=0.f;
  #pragma unroll
  for (int i = 0; i < 8; ++i){
    int f = f8 + i;
    float a = xtT[(size_t)f*NB + b];
    float c = xgT[(size_t)f*NB + b];
    vt[i]=a; vg[i]=c;
    st += a; sst += a*a; sg += c; ssg += c*c;
  }
  block_reduce4(st, sst, sg, ssg);
  float mt = st * (1.0f/2048.0f);
  float it = rsqrtf((sst - st*mt) * (1.0f/2047.0f) + EPSF);
  float mg = sg * (1.0f/2048.0f);
  float ig = rsqrtf((ssg - sg*mg) * (1.0f/2047.0f) + EPSF);
  bf16x8 a0, a1, a2;
  #pragma unroll
  for (int i = 0; i < 8; ++i){
    float nt = (vt[i]-mt)*it;
    float ng = (vg[i]-mg)*ig;
    float cv = nt * ftanh(ng);
    unsigned short s0,s1,s2; split3(cv,s0,s1,s2);
    a0[i]=(short)s0; a1[i]=(short)s1; a2[i]=(short)s2;
  }
  int c2 = f8 >> 5, kg = (f8 >> 3) & 3;
  size_t base = (size_t)c2*3072 + (b>>4)*512 + kg*128 + (b&15)*8;
  *(bf16x8*)(P + base)        = a0;
  *(bf16x8*)(P + base + 1024) = a1;
  *(bf16x8*)(P + base + 2048) = a2;
}

// norm over 512-groups (ddof=1) -> modc [B][16][512]
__global__ __launch_bounds__(256) void k_norm512(
    const float* __restrict__ ctx2T, float* __restrict__ modc){
  int b = blockIdx.x >> 4, kr = blockIdx.x & 15;
  int t = threadIdx.x;
  int base = kr*512;
  float v0 = ctx2T[(base + t      )*NB + b];
  float v1 = ctx2T[(base + 256 + t)*NB + b];
  float s = v0+v1, ss = v0*v0 + v1*v1, d0=0.f, d1=0.f;
  block_reduce4(s, ss, d0, d1);
  float m   = s * (1.0f/512.0f);
  float inv = rsqrtf((ss - s*m) * (1.0f/511.0f) + EPSF);
  modc[b*FFD + base + t      ] = (v0-m)*inv;
  modc[b*FFD + base + 256 + t] = (v1-m)*inv;
}

// scan pass: per-batch max_s/max_p + Sigma|v_s| partials. No plane stores.
__global__ __launch_bounds__(256) void k_scan(
    const float* __restrict__ modc,
    const float* __restrict__ convw, const float* __restrict__ convb,
    const float* __restrict__ wmod, const float* __restrict__ wstat,
    float* __restrict__ red, float* __restrict__ magpart){
  int b = blockIdx.x >> 4, chunk = blockIdx.x & 15;
  int t = threadIdx.x;
  __shared__ float lds[16*512];
  #pragma unroll
  for (int i = 0; i < 8; ++i){
    float4 v = *(const float4*)(modc + (size_t)b*FFD + (i*256 + t)*4);
    *(float4*)(lds + (i*256 + t)*4) = v;
  }
  float cw0 = convw[0]+convw[4]+convw[8]+convw[12];
  float cw1 = convw[1]+convw[5]+convw[9]+convw[13];
  float cw2 = convw[2]+convw[6]+convw[10]+convw[14];
  float cw3 = convw[3]+convw[7]+convw[11]+convw[15];
  float cb  = convb[0]+convb[1]+convb[2]+convb[3];
  __syncthreads();
  int w = t;
  float mxs = 0.f, mxp = 0.f, sas = 0.f;
  for (int it = 0; it < 16; ++it){
    int h = chunk*16 + it;
    int pix = h*WD + w;
    float r_, i_, p_, q_;
    pixel_core(lds, h, w, pix, cw0, cw1, cw2, cw3, cb, wmod, wstat,
               r_, i_, p_, q_);
    float as = sqrtf(r_*r_ + i_*i_ + EPSF);
    float ap = sqrtf(p_*p_ + q_*q_ + EPSF);
    mxs = fmaxf(mxs, as); mxp = fmaxf(mxp, ap);
    sas += as;
  }
  for (int off = 32; off > 0; off >>= 1){
    mxs = fmaxf(mxs, __shfl_down(mxs, off));
    mxp = fmaxf(mxp, __shfl_down(mxp, off));
    sas += __shfl_down(sas, off);
  }
  __shared__ float lred[12];
  int wid = t >> 6, lane = t & 63;
  if (lane == 0){ lred[wid] = mxs; lred[4+wid] = mxp; lred[8+wid] = sas; }
  __syncthreads();
  if (t == 0){
    float a = fmaxf(fmaxf(lred[0],lred[1]), fmaxf(lred[2],lred[3]));
    float p = fmaxf(fmaxf(lred[4],lred[5]), fmaxf(lred[6],lred[7]));
    float s = (lred[8]+lred[9])+(lred[10]+lred[11]);
    atomicMax((int*)&red[b],    __float_as_int(a));
    atomicMax((int*)&red[32+b], __float_as_int(p));
    magpart[b*16 + chunk] = s;
  }
}

// final: recompute pixels, combine with per-batch stats -> out
__global__ __launch_bounds__(256) void k_final(
    const float* __restrict__ modc,
    const float* __restrict__ convw, const float* __restrict__ convb,
    const float* __restrict__ wmod, const float* __restrict__ wstat,
    const float* __restrict__ red, const float* __restrict__ magpart,
    float* __restrict__ out){
  int b = blockIdx.x >> 4, chunk = blockIdx.x & 15;
  int t = threadIdx.x;
  __shared__ float lds[16*512];
  __shared__ float s_im;
  if (t < 16){
    float v = magpart[b*16 + t];
    for (int off = 8; off > 0; off >>= 1) v += __shfl_down(v, off);
    if (t == 0){
      float maxs = red[b];
      s_im = rsqrtf(v*(1.0f/65536.0f)/(maxs + EPSF) + EPSF);
    }
  }
  #pragma unroll
  for (int i = 0; i < 8; ++i){
    float4 v = *(const float4*)(modc + (size_t)b*FFD + (i*256 + t)*4);
    *(float4*)(lds + (i*256 + t)*4) = v;
  }
  float cw0 = convw[0]+convw[4]+convw[8]+convw[12];
  float cw1 = convw[1]+convw[5]+convw[9]+convw[13];
  float cw2 = convw[2]+convw[6]+convw[10]+convw[14];
  float cw3 = convw[3]+convw[7]+convw[11]+convw[15];
  float cb  = convb[0]+convb[1]+convb[2]+convb[3];
  __syncthreads();
  float im = s_im;
  float maxs = red[b], maxp = red[32+b];
  int w = t;
  for (int it = 0; it < 16; ++it){
    int h = chunk*16 + it;
    int pix = h*WD + w;
    float r_, i_, p_, q_;
    pixel_core(lds, h, w, pix, cw0, cw1, cw2, cw3, cb, wmod, wstat,
               r_, i_, p_, q_);
    float as = sqrtf(r_*r_ + i_*i_ + EPSF);
    float fs = (as/(maxs+EPSF))/(as+EPSF)*im;
    float2 A0 = *(const float2*)(wstat + (size_t)pix*2);
    float mwr = A0.x + fs*r_;
    float mwi = A0.y + fs*i_;
    float ap = sqrtf(p_*p_ + q_*q_ + EPSF);
    float fp = (ap/(maxp+EPSF))/(ap+EPSF);
    float mpr = fp*p_, mpi = fp*q_;
    float den = sqrtf(mpr*mpr + mpi*mpi + EPSF);
    out[(size_t)b*NPIX + pix] = (mwr*mpr + mwi*mpi)/den;
  }
}

// ---------- launch ----------

extern "C" void kernel_launch(void* const* d_in, const int* in_sizes, int n_in,
                              void* d_out, int out_size, void* d_ws, size_t ws_size,
                              hipStream_t stream){
  const float* x     = (const float*)d_in[0];
  const float* Win   = (const float*)d_in[1];
  const float* bin   = (const float*)d_in[2];
  const float* Wg    = (const float*)d_in[3];
  const float* bg    = (const float*)d_in[4];
  const float* Wt    = (const float*)d_in[5];
  const float* bt    = (const float*)d_in[6];
  const float* convw = (const float*)d_in[7];
  const float* convb = (const float*)d_in[8];
  const float* wstat = (const float*)d_in[9];
  const float* wmod  = (const float*)d_in[10];
  float* out = (float*)d_out;
  float* ws  = (float*)d_ws;

  // layout (floats); aliases are lifetime-disjoint:
  float* xtT   = ws;                       // dead after normgate
  float* xgT   = ws + 262144;              // dead after normgate
  float* ctx2T = ws;                       // alias xtT
  float* modc  = ws + 262144;              // alias xgT
  unsigned short* P2 = (unsigned short*)(ws + 524288);   // ctx pack (256 chunks)
  unsigned short* P1 = (unsigned short*)(ws + 917504);   // x pack (32 chunks)
  float* Cp    = ws + 966656;              // up to 32 x FFD*32 = 8.39M floats
  float* red     = ws + 9355264;           // max_s[32], max_p[32]
  float* magpart = ws + 9355328;           // [32][16]

  k_prep<<<16, 256, 0, stream>>>(x, P1, red);
  // GEMM1: K=1024, grid (fb=256, kc=4, z=2), S=4 per matrix
  k_gemm_stream<<<dim3(256,4,2), 128, 0, stream>>>(Win, Wg, P1,
                                                   Cp, CTXD, 4ull*FFD*32);
  k_reduce1<<<2048, 256, 0, stream>>>(Cp, bin, bg, xtT, xgT);
  k_normgate<<<128, 256, 0, stream>>>(xtT, xgT, P2);
  // GEMM2: K=8192, grid (fb=256, kc=32), S=32
  k_gemm_stream<<<dim3(256,32,1), 128, 0, stream>>>(Wt, Wt, P2,
                                                    Cp, FFD, 0);
  k_reduce2<<<1024, 256, 0, stream>>>(Cp, bt, ctx2T);
  k_norm512<<<512, 256, 0, stream>>>(ctx2T, modc);
  k_scan<<<512, 256, 0, stream>>>(modc, convw, convb, wmod, wstat, red, magpart);
  k_final<<<512, 256, 0, stream>>>(modc, convw, convb, wmod, wstat, red,
                                   magpart, out);
}

// Round 12
// 160.681 us; speedup vs baseline: 1.0807x; 1.0807x over previous
//
#include <hip/hip_runtime.h>
#include <cstddef>

#define NB   32
#define CTXD 1024
#define FFD  8192
#define HD   256
#define WD   256
#define NPIX 65536
#define EPSF 1e-12f

typedef __attribute__((ext_vector_type(8))) short bf16x8;
typedef __attribute__((ext_vector_type(4))) float f32x4;

// ---------- helpers ----------

__device__ __forceinline__ float ftanh(float x){
  float ax = fabsf(x);
  float e  = __expf(2.0f*ax);
  float r  = 1.0f - 2.0f*__builtin_amdgcn_rcpf(e + 1.0f);
  return copysignf(r, x);
}

__device__ __forceinline__ unsigned short f2bf(float f){
  unsigned u = __float_as_uint(f);
  unsigned r = (u + 0x7FFFu + ((u >> 16) & 1u)) >> 16;   // RTNE
  return (unsigned short)r;
}
__device__ __forceinline__ float bf2f(unsigned short s){
  return __uint_as_float((unsigned)s << 16);
}

// split f32 -> 3 bf16 terms (residual ~2^-27 relative)
__device__ __forceinline__ void split3(float f, unsigned short& s0,
                                       unsigned short& s1, unsigned short& s2){
  s0 = f2bf(f);
  float r1 = f - bf2f(s0);
  s1 = f2bf(r1);
  float r2 = r1 - bf2f(s1);
  s2 = f2bf(r2);
}

// async global->LDS: lane L's 16B lands at ldst + L*16; global src per-lane
__device__ __forceinline__ void gload_lds16(const void* g, void* l){
  __builtin_amdgcn_global_load_lds(
      (__attribute__((address_space(1))) void*)g,
      (__attribute__((address_space(3))) void*)l, 16, 0, 0);
}

__device__ __forceinline__ void block_reduce4(float& a, float& b, float& c, float& d){
  for (int off = 32; off > 0; off >>= 1){
    a += __shfl_down(a, off); b += __shfl_down(b, off);
    c += __shfl_down(c, off); d += __shfl_down(d, off);
  }
  __shared__ float lds[16];
  int wid = threadIdx.x >> 6, lane = threadIdx.x & 63;
  if (lane == 0){ lds[wid*4+0]=a; lds[wid*4+1]=b; lds[wid*4+2]=c; lds[wid*4+3]=d; }
  __syncthreads();
  a = (lds[0]+lds[4])+(lds[8]+lds[12]);
  b = (lds[1]+lds[5])+(lds[9]+lds[13]);
  c = (lds[2]+lds[6])+(lds[10]+lds[14]);
  d = (lds[3]+lds[7])+(lds[11]+lds[15]);
}

// per-pixel recompute core shared by k_scan / k_final (must stay identical)
__device__ __forceinline__ void pixel_core(
    const float* __restrict__ lds, int h, int w, int pix,
    float cw0, float cw1, float cw2, float cw3, float cb,
    const float* __restrict__ wmod, const float* __restrict__ wstat,
    float& r_, float& i_, float& p_, float& q_){
  float sk[4];
  #pragma unroll
  for (int k = 0; k < 4; ++k){
    float acc = 0.f;
    #pragma unroll
    for (int r = 0; r < 4; ++r){
      int kr = k*4 + r;
      float u  = lds[kr*512 + h];
      float vv = lds[kr*512 + 256 + w];
      float tt = ftanh(u*vv);
      float cwr = (r==0)?cw0:(r==1)?cw1:(r==2)?cw2:cw3;
      acc += (k==0) ? cwr*tt : tt;
    }
    sk[k] = acc;
  }
  sk[0] += cb;
  float m0 = sk[0]*wmod[0*NPIX+pix];
  float m1 = sk[1]*wmod[1*NPIX+pix];
  float m2 = sk[2]*wmod[2*NPIX+pix];
  float m3 = sk[3]*wmod[3*NPIX+pix];
  float2 A1 = *(const float2*)(wstat + (size_t)(NPIX + pix)*2);
  r_ = A1.x*m0 - A1.y*m1;
  i_ = A1.x*m1 - A1.y*m0;
  p_ = m2; q_ = m3;
}

// ---------- kernels ----------

// split x [32][1024] f32 -> packed B-fragment layout, zero red[]
__global__ __launch_bounds__(256) void k_prep(
    const float* __restrict__ x, unsigned short* __restrict__ P,
    float* __restrict__ red){
  int g = blockIdx.x*256 + threadIdx.x;      // 4096 = 32 rows x 128 groups
  if (g < 64) red[g] = 0.0f;
  int b = g >> 7, grp = g & 127;
  int koff = grp*8;
  int c = grp >> 2, kg = grp & 3;
  const float* src = x + (size_t)b*CTXD + koff;
  float4 v0 = *(const float4*)(src), v1 = *(const float4*)(src+4);
  float vv[8] = {v0.x,v0.y,v0.z,v0.w,v1.x,v1.y,v1.z,v1.w};
  bf16x8 a0, a1, a2;
  #pragma unroll
  for (int e = 0; e < 8; ++e){
    unsigned short s0,s1,s2; split3(vv[e],s0,s1,s2);
    a0[e]=(short)s0; a1[e]=(short)s1; a2[e]=(short)s2;
  }
  size_t base = (size_t)c*3072 + (b>>4)*512 + kg*128 + (b&15)*8;
  *(bf16x8*)(P + base)        = a0;
  *(bf16x8*)(P + base + 1024) = a1;
  *(bf16x8*)(P + base + 2048) = a2;
}

// B-reuse streaming split-bf16 MFMA GEMM.
// Block = 4 waves x 128 features x kslice 256. B-pack slice (48KB) staged to
// LDS once; W staged per-step (128x32k, dbuf, per-wave-owned quarter ->
// no in-loop barriers). Each wave computes 2 row-tiles reusing B fragments.
// Cp[z][kc][f][b] partials.
__global__ __launch_bounds__(256) void k_gemm_reuse(
    const float* __restrict__ W0, const float* __restrict__ W1,
    const unsigned short* __restrict__ BP,
    float* __restrict__ Cp, int K, size_t zstride){
  __shared__ float wtile[2][4096];           // 2 x (128 rows x 32 k) = 32KB
  __shared__ unsigned short bpack[24576];    // 8 chunks x 3072 = 48KB
  const int t = threadIdx.x;
  const int wv = t >> 6, lane = t & 63;
  const int row = lane & 15, kg = lane >> 4;
  const int f0 = blockIdx.x * 128;
  const int kc = blockIdx.y;
  const float* __restrict__ W = blockIdx.z ? W1 : W0;
  const int kb = kc * 256;                   // k float-offset of slice

  // one-time B stage: 48 x 1KB calls, 12 per wave
  {
    const unsigned short* bsrc = BP + (size_t)(kc*8)*3072;
    #pragma unroll
    for (int i = 0; i < 12; ++i){
      int call = wv*12 + i;
      gload_lds16(bsrc + call*512 + lane*8, bpack + call*512);
    }
  }
  // W stage for step s into wtile[buf]; wave stages its own 32 rows as
  // 4 x 1KB calls (8 rows x 128B each). Source piece XOR-swizzled (T21).
  auto stageW = [&](int buf, int s){
    const int kbase = kb + s*32;
    #pragma unroll
    for (int i = 0; i < 4; ++i){
      int call = wv*4 + i;
      const float* src = W + (size_t)(f0 + call*8 + (lane>>3))*K + kbase
                           + (((lane&7) ^ ((lane>>3)&7)) << 2);
      gload_lds16(src, &wtile[buf][call*256]);
    }
  };

  stageW(0, 0);
  asm volatile("s_waitcnt vmcnt(0)" ::: "memory");
  __syncthreads();                            // B + first W tile visible

  f32x4 acc0l={0.f,0.f,0.f,0.f}, acc0h={0.f,0.f,0.f,0.f};
  f32x4 acc1l={0.f,0.f,0.f,0.f}, acc1h={0.f,0.f,0.f,0.f};
  int cur = 0;
  const int sw = row & 7;

  for (int s = 0; s < 8; ++s){
    if (s + 1 < 8) stageW(cur ^ 1, s + 1);
    asm volatile("s_waitcnt vmcnt(4)" ::: "memory");
    __builtin_amdgcn_sched_barrier(0);
    // B fragments for this chunk (LDS, shared across both row-tiles)
    const unsigned short* bch = bpack + s*3072 + kg*128 + row*8;
    bf16x8 b0 = *(const bf16x8*)(bch);
    bf16x8 b1 = *(const bf16x8*)(bch +  512);
    bf16x8 b2 = *(const bf16x8*)(bch + 1024);
    bf16x8 b3 = *(const bf16x8*)(bch + 1536);
    bf16x8 b4 = *(const bf16x8*)(bch + 2048);
    bf16x8 b5 = *(const bf16x8*)(bch + 2560);
    #pragma unroll
    for (int T = 0; T < 2; ++T){
      const float* wr = &wtile[cur][(wv*32 + T*16 + row)*32];
      float4 lo = *(const float4*)(wr + (((2*kg  ) ^ sw) << 2));
      float4 hi = *(const float4*)(wr + (((2*kg+1) ^ sw) << 2));
      bf16x8 a0, a1, a2;
      float wv8[8] = {lo.x,lo.y,lo.z,lo.w,hi.x,hi.y,hi.z,hi.w};
      #pragma unroll
      for (int e = 0; e < 8; ++e){
        unsigned short s0,s1,s2; split3(wv8[e],s0,s1,s2);
        a0[e]=(short)s0; a1[e]=(short)s1; a2[e]=(short)s2;
      }
      f32x4 al = T ? acc1l : acc0l, ah = T ? acc1h : acc0h;
      al = __builtin_amdgcn_mfma_f32_16x16x32_bf16(a0, b0, al, 0,0,0);
      ah = __builtin_amdgcn_mfma_f32_16x16x32_bf16(a0, b1, ah, 0,0,0);
      al = __builtin_amdgcn_mfma_f32_16x16x32_bf16(a0, b2, al, 0,0,0);
      ah = __builtin_amdgcn_mfma_f32_16x16x32_bf16(a0, b3, ah, 0,0,0);
      al = __builtin_amdgcn_mfma_f32_16x16x32_bf16(a1, b0, al, 0,0,0);
      ah = __builtin_amdgcn_mfma_f32_16x16x32_bf16(a1, b1, ah, 0,0,0);
      al = __builtin_amdgcn_mfma_f32_16x16x32_bf16(a0, b4, al, 0,0,0);
      ah = __builtin_amdgcn_mfma_f32_16x16x32_bf16(a0, b5, ah, 0,0,0);
      al = __builtin_amdgcn_mfma_f32_16x16x32_bf16(a1, b2, al, 0,0,0);
      ah = __builtin_amdgcn_mfma_f32_16x16x32_bf16(a1, b3, ah, 0,0,0);
      al = __builtin_amdgcn_mfma_f32_16x16x32_bf16(a2, b0, al, 0,0,0);
      ah = __builtin_amdgcn_mfma_f32_16x16x32_bf16(a2, b1, ah, 0,0,0);
      if (T){ acc1l = al; acc1h = ah; } else { acc0l = al; acc0h = ah; }
    }
    cur ^= 1;
  }

  float* __restrict__ C = Cp + (size_t)blockIdx.z*zstride + (size_t)kc*(FFD*32);
  #pragma unroll
  for (int r = 0; r < 4; ++r){               // C/D: col=lane&15, row=kg*4+r
    int fA = f0 + wv*32 + kg*4 + r;
    int fB = fA + 16;
    C[(size_t)fA*32 + row]      = acc0l[r];
    C[(size_t)fA*32 + 16 + row] = acc0h[r];
    C[(size_t)fB*32 + row]      = acc1l[r];
    C[(size_t)fB*32 + 16 + row] = acc1h[r];
  }
}

// reduce for GEMM1 (both matrices), S=4
__global__ __launch_bounds__(256) void k_reduce1(
    const float* __restrict__ Cp, const float* __restrict__ bin,
    const float* __restrict__ bg, float* __restrict__ xtT,
    float* __restrict__ xgT){
  int g = blockIdx.x*256 + threadIdx.x;          // 524288
  int m = g >> 18, idx = g & 262143;
  int f = idx >> 5;
  const float* __restrict__ cp = Cp + (size_t)m*(4ull*FFD*32);
  float s = (m ? bg : bin)[f];
  #pragma unroll
  for (int sI = 0; sI < 4; ++sI) s += cp[(size_t)sI*(FFD*32) + idx];
  (m ? xgT : xtT)[idx] = s;
}

// reduce for GEMM2, S=32
__global__ __launch_bounds__(256) void k_reduce2(
    const float* __restrict__ Cp, const float* __restrict__ bias,
    float* __restrict__ outT){
  int g = blockIdx.x*256 + threadIdx.x;          // 262144
  int f = g >> 5;
  float s = bias[f];
  #pragma unroll
  for (int sI = 0; sI < 32; ++sI) s += Cp[(size_t)sI*(FFD*32) + g];
  outT[g] = s;
}

// norm over 2048-groups (ddof=1); ctx = nt*tanh(ng) -> packed B-fragment layout
__global__ __launch_bounds__(256) void k_normgate(
    const float* __restrict__ xtT, const float* __restrict__ xgT,
    unsigned short* __restrict__ P){
  int b = blockIdx.x >> 2, g4 = blockIdx.x & 3;
  int t = threadIdx.x;
  int f8 = g4*2048 + t*8;
  float vt[8], vg[8];
  float st=0.f, sst=0.f, sg=0.f, ssg=0.f;
  #pragma unroll
  for (int i = 0; i < 8; ++i){
    int f = f8 + i;
    float a = xtT[(size_t)f*NB + b];
    float c = xgT[(size_t)f*NB + b];
    vt[i]=a; vg[i]=c;
    st += a; sst += a*a; sg += c; ssg += c*c;
  }
  block_reduce4(st, sst, sg, ssg);
  float mt = st * (1.0f/2048.0f);
  float it = rsqrtf((sst - st*mt) * (1.0f/2047.0f) + EPSF);
  float mg = sg * (1.0f/2048.0f);
  float ig = rsqrtf((ssg - sg*mg) * (1.0f/2047.0f) + EPSF);
  bf16x8 a0, a1, a2;
  #pragma unroll
  for (int i = 0; i < 8; ++i){
    float nt = (vt[i]-mt)*it;
    float ng = (vg[i]-mg)*ig;
    float cv = nt * ftanh(ng);
    unsigned short s0,s1,s2; split3(cv,s0,s1,s2);
    a0[i]=(short)s0; a1[i]=(short)s1; a2[i]=(short)s2;
  }
  int c2 = f8 >> 5, kg = (f8 >> 3) & 3;
  size_t base = (size_t)c2*3072 + (b>>4)*512 + kg*128 + (b&15)*8;
  *(bf16x8*)(P + base)        = a0;
  *(bf16x8*)(P + base + 1024) = a1;
  *(bf16x8*)(P + base + 2048) = a2;
}

// norm over 512-groups (ddof=1) -> modc [B][16][512]
__global__ __launch_bounds__(256) void k_norm512(
    const float* __restrict__ ctx2T, float* __restrict__ modc){
  int b = blockIdx.x >> 4, kr = blockIdx.x & 15;
  int t = threadIdx.x;
  int base = kr*512;
  float v0 = ctx2T[(base + t      )*NB + b];
  float v1 = ctx2T[(base + 256 + t)*NB + b];
  float s = v0+v1, ss = v0*v0 + v1*v1, d0=0.f, d1=0.f;
  block_reduce4(s, ss, d0, d1);
  float m   = s * (1.0f/512.0f);
  float inv = rsqrtf((ss - s*m) * (1.0f/511.0f) + EPSF);
  modc[b*FFD + base + t      ] = (v0-m)*inv;
  modc[b*FFD + base + 256 + t] = (v1-m)*inv;
}

// scan pass: per-batch max_s/max_p + Sigma|v_s| partials. No plane stores.
__global__ __launch_bounds__(256) void k_scan(
    const float* __restrict__ modc,
    const float* __restrict__ convw, const float* __restrict__ convb,
    const float* __restrict__ wmod, const float* __restrict__ wstat,
    float* __restrict__ red, float* __restrict__ magpart){
  int b = blockIdx.x >> 4, chunk = blockIdx.x & 15;
  int t = threadIdx.x;
  __shared__ float lds[16*512];
  #pragma unroll
  for (int i = 0; i < 8; ++i){
    float4 v = *(const float4*)(modc + (size_t)b*FFD + (i*256 + t)*4);
    *(float4*)(lds + (i*256 + t)*4) = v;
  }
  float cw0 = convw[0]+convw[4]+convw[8]+convw[12];
  float cw1 = convw[1]+convw[5]+convw[9]+convw[13];
  float cw2 = convw[2]+convw[6]+convw[10]+convw[14];
  float cw3 = convw[3]+convw[7]+convw[11]+convw[15];
  float cb  = convb[0]+convb[1]+convb[2]+convb[3];
  __syncthreads();
  int w = t;
  float mxs = 0.f, mxp = 0.f, sas = 0.f;
  for (int it = 0; it < 16; ++it){
    int h = chunk*16 + it;
    int pix = h*WD + w;
    float r_, i_, p_, q_;
    pixel_core(lds, h, w, pix, cw0, cw1, cw2, cw3, cb, wmod, wstat,
               r_, i_, p_, q_);
    float as = sqrtf(r_*r_ + i_*i_ + EPSF);
    float ap = sqrtf(p_*p_ + q_*q_ + EPSF);
    mxs = fmaxf(mxs, as); mxp = fmaxf(mxp, ap);
    sas += as;
  }
  for (int off = 32; off > 0; off >>= 1){
    mxs = fmaxf(mxs, __shfl_down(mxs, off));
    mxp = fmaxf(mxp, __shfl_down(mxp, off));
    sas += __shfl_down(sas, off);
  }
  __shared__ float lred[12];
  int wid = t >> 6, lane = t & 63;
  if (lane == 0){ lred[wid] = mxs; lred[4+wid] = mxp; lred[8+wid] = sas; }
  __syncthreads();
  if (t == 0){
    float a = fmaxf(fmaxf(lred[0],lred[1]), fmaxf(lred[2],lred[3]));
    float p = fmaxf(fmaxf(lred[4],lred[5]), fmaxf(lred[6],lred[7]));
    float s = (lred[8]+lred[9])+(lred[10]+lred[11]);
    atomicMax((int*)&red[b],    __float_as_int(a));
    atomicMax((int*)&red[32+b], __float_as_int(p));
    magpart[b*16 + chunk] = s;
  }
}

// final: recompute pixels, combine with per-batch stats -> out
__global__ __launch_bounds__(256) void k_final(
    const float* __restrict__ modc,
    const float* __restrict__ convw, const float* __restrict__ convb,
    const float* __restrict__ wmod, const float* __restrict__ wstat,
    const float* __restrict__ red, const float* __restrict__ magpart,
    float* __restrict__ out){
  int b = blockIdx.x >> 4, chunk = blockIdx.x & 15;
  int t = threadIdx.x;
  __shared__ float lds[16*512];
  __shared__ float s_im;
  if (t < 16){
    float v = magpart[b*16 + t];
    for (int off = 8; off > 0; off >>= 1) v += __shfl_down(v, off);
    if (t == 0){
      float maxs = red[b];
      s_im = rsqrtf(v*(1.0f/65536.0f)/(maxs + EPSF) + EPSF);
    }
  }
  #pragma unroll
  for (int i = 0; i < 8; ++i){
    float4 v = *(const float4*)(modc + (size_t)b*FFD + (i*256 + t)*4);
    *(float4*)(lds + (i*256 + t)*4) = v;
  }
  float cw0 = convw[0]+convw[4]+convw[8]+convw[12];
  float cw1 = convw[1]+convw[5]+convw[9]+convw[13];
  float cw2 = convw[2]+convw[6]+convw[10]+convw[14];
  float cw3 = convw[3]+convw[7]+convw[11]+convw[15];
  float cb  = convb[0]+convb[1]+convb[2]+convb[3];
  __syncthreads();
  float im = s_im;
  float maxs = red[b], maxp = red[32+b];
  int w = t;
  for (int it = 0; it < 16; ++it){
    int h = chunk*16 + it;
    int pix = h*WD + w;
    float r_, i_, p_, q_;
    pixel_core(lds, h, w, pix, cw0, cw1, cw2, cw3, cb, wmod, wstat,
               r_, i_, p_, q_);
    float as = sqrtf(r_*r_ + i_*i_ + EPSF);
    float fs = (as/(maxs+EPSF))/(as+EPSF)*im;
    float2 A0 = *(const float2*)(wstat + (size_t)pix*2);
    float mwr = A0.x + fs*r_;
    float mwi = A0.y + fs*i_;
    float ap = sqrtf(p_*p_ + q_*q_ + EPSF);
    float fp = (ap/(maxp+EPSF))/(ap+EPSF);
    float mpr = fp*p_, mpi = fp*q_;
    float den = sqrtf(mpr*mpr + mpi*mpi + EPSF);
    out[(size_t)b*NPIX + pix] = (mwr*mpr + mwi*mpi)/den;
  }
}

// ---------- launch ----------

extern "C" void kernel_launch(void* const* d_in, const int* in_sizes, int n_in,
                              void* d_out, int out_size, void* d_ws, size_t ws_size,
                              hipStream_t stream){
  const float* x     = (const float*)d_in[0];
  const float* Win   = (const float*)d_in[1];
  const float* bin   = (const float*)d_in[2];
  const float* Wg    = (const float*)d_in[3];
  const float* bg    = (const float*)d_in[4];
  const float* Wt    = (const float*)d_in[5];
  const float* bt    = (const float*)d_in[6];
  const float* convw = (const float*)d_in[7];
  const float* convb = (const float*)d_in[8];
  const float* wstat = (const float*)d_in[9];
  const float* wmod  = (const float*)d_in[10];
  float* out = (float*)d_out;
  float* ws  = (float*)d_ws;

  // layout (floats); aliases are lifetime-disjoint:
  float* xtT   = ws;                       // dead after normgate
  float* xgT   = ws + 262144;              // dead after normgate
  float* ctx2T = ws;                       // alias xtT
  float* modc  = ws + 262144;              // alias xgT
  unsigned short* P2 = (unsigned short*)(ws + 524288);   // ctx pack (256 chunks)
  unsigned short* P1 = (unsigned short*)(ws + 917504);   // x pack (32 chunks)
  float* Cp    = ws + 966656;              // up to 32 x FFD*32 = 8.39M floats
  float* red     = ws + 9355264;           // max_s[32], max_p[32]
  float* magpart = ws + 9355328;           // [32][16]

  k_prep<<<16, 256, 0, stream>>>(x, P1, red);
  // GEMM1: K=1024, grid (f=64, kc=4, z=2), kslice=256
  k_gemm_reuse<<<dim3(64,4,2), 256, 0, stream>>>(Win, Wg, P1,
                                                 Cp, CTXD, 4ull*FFD*32);
  k_reduce1<<<2048, 256, 0, stream>>>(Cp, bin, bg, xtT, xgT);
  k_normgate<<<128, 256, 0, stream>>>(xtT, xgT, P2);
  // GEMM2: K=8192, grid (f=64, kc=32), kslice=256
  k_gemm_reuse<<<dim3(64,32,1), 256, 0, stream>>>(Wt, Wt, P2,
                                                  Cp, FFD, 0);
  k_reduce2<<<1024, 256, 0, stream>>>(Cp, bt, ctx2T);
  k_norm512<<<512, 256, 0, stream>>>(ctx2T, modc);
  k_scan<<<512, 256, 0, stream>>>(modc, convw, convb, wmod, wstat, red, magpart);
  k_final<<<512, 256, 0, stream>>>(modc, convw, convb, wmod, wstat, red,
                                   magpart, out);
}